// Round 1
// baseline (108.402 us; speedup 1.0000x reference)
//
#include <hip/hip_runtime.h>
#include <math.h>

// Segment max: out[seg][d] = max over rows r with batch[r]==seg of x[r][d].
// batch is sorted; one block per segment; binary search for boundaries.
// D = 128 floats per row = 32 float4.

__global__ __launch_bounds__(256) void seg_max_kernel(
    const float* __restrict__ x, const int* __restrict__ batch,
    float* __restrict__ out, int N, int B) {
    const int seg = blockIdx.x;

    // lower_bound(seg): first i with batch[i] >= seg
    int lo = 0, hi = N;
    while (lo < hi) {
        int mid = (lo + hi) >> 1;
        if (batch[mid] < seg) lo = mid + 1; else hi = mid;
    }
    const int start = lo;
    // upper_bound(seg): first i with batch[i] > seg
    hi = N;
    while (lo < hi) {
        int mid = (lo + hi) >> 1;
        if (batch[mid] <= seg) lo = mid + 1; else hi = mid;
    }
    const int end = lo;

    const int tid  = threadIdx.x;
    const int col4 = tid & 31;   // which float4 of the row (32 * 4 = 128 floats)
    const int rg   = tid >> 5;   // row group 0..7

    float4 m = make_float4(-INFINITY, -INFINITY, -INFINITY, -INFINITY);
    const float4* __restrict__ x4 = reinterpret_cast<const float4*>(x);

    // Streaming, coalesced: half-wave (32 lanes) covers one full 512B row.
    for (int r = start + rg; r < end; r += 8) {
        float4 v = x4[(size_t)r * 32 + col4];
        m.x = fmaxf(m.x, v.x);
        m.y = fmaxf(m.y, v.y);
        m.z = fmaxf(m.z, v.z);
        m.w = fmaxf(m.w, v.w);
    }

    // Reduce the 8 row groups (tid = rg*32 + col4, so stride-32 pairs share col4).
    __shared__ float4 smem[256];
    smem[tid] = m;
    __syncthreads();
    #pragma unroll
    for (int step = 128; step >= 32; step >>= 1) {
        if (tid < step) {
            float4 o = smem[tid + step];
            float4 c = smem[tid];
            c.x = fmaxf(c.x, o.x);
            c.y = fmaxf(c.y, o.y);
            c.z = fmaxf(c.z, o.z);
            c.w = fmaxf(c.w, o.w);
            smem[tid] = c;
        }
        __syncthreads();
    }
    if (tid < 32) {
        reinterpret_cast<float4*>(out)[(size_t)seg * 32 + tid] = smem[tid];
    }
}

extern "C" void kernel_launch(void* const* d_in, const int* in_sizes, int n_in,
                              void* d_out, int out_size, void* d_ws, size_t ws_size,
                              hipStream_t stream) {
    const float* x     = (const float*)d_in[0];
    const int*   batch = (const int*)d_in[1];
    float*       out   = (float*)d_out;

    const int D = 128;
    const int N = in_sizes[0] / D;
    const int B = out_size / D;   // 2048 segments

    seg_max_kernel<<<B, 256, 0, stream>>>(x, batch, out, N, B);
}

// Round 2
// 105.254 us; speedup vs baseline: 1.0299x; 1.0299x over previous
//
#include <hip/hip_runtime.h>
#include <math.h>

// Segment max: out[seg][d] = max over rows r with batch[r]==seg of x[r][d].
// batch is sorted int32, B segments, D=128 floats/row = 32 float4.
//
// Kernel 1: B+1 threads binary-search segment boundaries in parallel -> ws.
// Kernel 2: one block per segment, fully-coalesced float4 streaming max with
//           unroll-4 / 4 accumulators for load ILP, LDS tree reduce, store.

__global__ __launch_bounds__(256) void find_bounds_kernel(
    const int* __restrict__ batch, int* __restrict__ bounds, int N, int B) {
    int b = blockIdx.x * 256 + threadIdx.x;
    if (b > B) return;
    if (b == B) { bounds[B] = N; return; }
    // lower_bound: first i with batch[i] >= b
    int lo = 0, hi = N;
    while (lo < hi) {
        int mid = (lo + hi) >> 1;
        if (batch[mid] < b) lo = mid + 1; else hi = mid;
    }
    bounds[b] = lo;
}

__device__ __forceinline__ float4 max4(float4 a, float4 b) {
    a.x = fmaxf(a.x, b.x);
    a.y = fmaxf(a.y, b.y);
    a.z = fmaxf(a.z, b.z);
    a.w = fmaxf(a.w, b.w);
    return a;
}

__global__ __launch_bounds__(256, 8) void seg_max_kernel(
    const float* __restrict__ x, const int* __restrict__ bounds,
    float* __restrict__ out) {
    const int seg   = blockIdx.x;
    const int start = bounds[seg];      // wave-uniform broadcast loads
    const int end   = bounds[seg + 1];

    const int tid  = threadIdx.x;
    const int col4 = tid & 31;   // which float4 of the row (32 * 16B = 512B row)
    const int rg   = tid >> 5;   // row group 0..7

    const float4* __restrict__ x4 = reinterpret_cast<const float4*>(x);
    const float4 ninf = make_float4(-INFINITY, -INFINITY, -INFINITY, -INFINITY);
    float4 m0 = ninf, m1 = ninf, m2 = ninf, m3 = ninf;

    // Coalesced streaming: half-wave (32 lanes) covers one contiguous 512B row.
    // Unroll-4 with independent accumulators: 4 loads in flight per wave.
    int r = start + rg;
    for (; r + 24 < end; r += 32) {
        float4 v0 = x4[(size_t)(r)      * 32 + col4];
        float4 v1 = x4[(size_t)(r + 8)  * 32 + col4];
        float4 v2 = x4[(size_t)(r + 16) * 32 + col4];
        float4 v3 = x4[(size_t)(r + 24) * 32 + col4];
        m0 = max4(m0, v0);
        m1 = max4(m1, v1);
        m2 = max4(m2, v2);
        m3 = max4(m3, v3);
    }
    for (; r < end; r += 8) {
        m0 = max4(m0, x4[(size_t)r * 32 + col4]);
    }
    float4 m = max4(max4(m0, m1), max4(m2, m3));

    // Reduce the 8 row groups (tid = rg*32 + col4; stride-32 pairs share col4).
    __shared__ float4 smem[256];
    smem[tid] = m;
    __syncthreads();
    #pragma unroll
    for (int step = 128; step >= 32; step >>= 1) {
        if (tid < step) {
            smem[tid] = max4(smem[tid], smem[tid + step]);
        }
        __syncthreads();
    }
    if (tid < 32) {
        reinterpret_cast<float4*>(out)[(size_t)seg * 32 + tid] = smem[tid];
    }
}

extern "C" void kernel_launch(void* const* d_in, const int* in_sizes, int n_in,
                              void* d_out, int out_size, void* d_ws, size_t ws_size,
                              hipStream_t stream) {
    const float* x     = (const float*)d_in[0];
    const int*   batch = (const int*)d_in[1];
    float*       out   = (float*)d_out;
    int*         bounds = (int*)d_ws;   // (B+1) ints

    const int D = 128;
    const int N = in_sizes[0] / D;
    const int B = out_size / D;   // 2048 segments

    find_bounds_kernel<<<(B + 1 + 255) / 256, 256, 0, stream>>>(batch, bounds, N, B);
    seg_max_kernel<<<B, 256, 0, stream>>>(x, bounds, out);
}